// Round 6
// baseline (93.701 us; speedup 1.0000x reference)
//
#include <hip/hip_runtime.h>

#define N_NODES 40000
#define N_EDGES 160000
#define N_FEATS 74
#define DD 1024
#define HD 3072
#define N_GRAPHS 800

typedef float v2f __attribute__((ext_vector_type(2)));

__device__ __forceinline__ float waveReduceSum(float v) {
    #pragma unroll
    for (int off = 32; off > 0; off >>= 1)
        v += __shfl_down(v, off, 64);
    return v;
}
__device__ __forceinline__ float lrelu02(float x) { return x > 0.f ? x : 0.2f * x; }

// packed 2xf32 atomic add; falls back to 2 scalar atomics if builtin missing
__device__ __forceinline__ void pk_add(float* p, float a, float b) {
#if __has_builtin(__builtin_amdgcn_global_atomic_fadd_v2f32)
    typedef __attribute__((address_space(1))) v2f gv2f;
    v2f val = {a, b};
    (void)__builtin_amdgcn_global_atomic_fadd_v2f32((gv2f*)p, val);
#else
    atomicAdd(p + 0, a);
    atomicAdd(p + 1, b);
#endif
}

// ---- K1: v = W1@W2 (3072), c0 = b1.W2+b2, wl9 L/R columns (don't need v) ----
__global__ void kV(const float* __restrict__ W1, const float* __restrict__ W2,
                   const float* __restrict__ b1, const float* __restrict__ b2,
                   const float* __restrict__ W, const float* __restrict__ al,
                   const float* __restrict__ ar,
                   float* __restrict__ v, float* __restrict__ c0,
                   float* __restrict__ wl9) {
    int w = blockIdx.x * 4 + (threadIdx.x >> 6);
    int lane = threadIdx.x & 63;
    if (w < HD) {
        const float* row = W1 + (size_t)w * DD;
        float acc = 0.f;
        for (int t = lane; t < DD; t += 64) acc += row[t] * W2[t];
        acc = waveReduceSum(acc);
        if (!lane) v[w] = acc;
    } else if (w == HD) {
        float acc = 0.f;
        for (int t = lane; t < DD; t += 64) acc += b1[t] * W2[t];
        acc = waveReduceSum(acc);
        if (!lane) *c0 = acc + b2[0];
    } else if (w < HD + 1 + N_FEATS * 3) {
        int w2 = w - HD - 1;
        int f = w2 / 3, h = w2 - f * 3;
        const float* rw = W + (size_t)f * HD + h * DD;
        const float* pl = al + h * DD;
        const float* pr = ar + h * DD;
        float aL = 0.f, aR = 0.f;
        for (int t = lane; t < DD; t += 64) {
            float x = rw[t];
            aL += x * pl[t]; aR += x * pr[t];
        }
        aL = waveReduceSum(aL); aR = waveReduceSum(aR);
        if (!lane) { wl9[f * 9 + h] = aL; wl9[f * 9 + 3 + h] = aR; }
    }
}

// ---- K2: wl9 V column = W_col . v ; bgv = bias_gat . v (need v) ----
__global__ void kProj(const float* __restrict__ W, const float* __restrict__ v,
                      const float* __restrict__ bias,
                      float* __restrict__ wl9, float* __restrict__ bgv) {
    int w = blockIdx.x * 4 + (threadIdx.x >> 6);
    int lane = threadIdx.x & 63;
    if (w < N_FEATS * 3) {
        int f = w / 3, h = w - f * 3;
        const float* rw = W + (size_t)f * HD + h * DD;
        const float* pv = v + h * DD;
        float aV = 0.f;
        for (int t = lane; t < DD; t += 64) aV += rw[t] * pv[t];
        aV = waveReduceSum(aV);
        if (!lane) wl9[f * 9 + 6 + h] = aV;
    } else if (w == N_FEATS * 3) {
        float acc = 0.f;
        for (int t = lane; t < HD; t += 64) acc += bias[t] * v[t];
        acc = waveReduceSum(acc);
        if (!lane) *bgv = acc;
    }
}

// ---- K3: node projections; sn = [el|hv] packed 32B; er separate; zero nd ----
__global__ __launch_bounds__(256) void kNode(const float* __restrict__ feats,
                      const float* __restrict__ wl9,
                      float4* __restrict__ sn4,   // [N][2]: {el0..2,_},{hv0..2,_}
                      float4* __restrict__ er4,   // [N]
                      float4* __restrict__ nd4) { // [N][2] zeroed here
    __shared__ float tile[256 * 75];
    __shared__ float lw[N_FEATS * 9];
    int t = threadIdx.x;
    int base = blockIdx.x * 256;
    int nvalid = min(256, N_NODES - base);
    for (int i = t; i < N_FEATS * 9; i += 256) lw[i] = wl9[i];
    int total = nvalid * N_FEATS;
    const float* srcp = feats + (size_t)base * N_FEATS;
    for (int i = t; i < total; i += 256) {
        int node = i / N_FEATS;
        int f = i - node * N_FEATS;
        tile[node * 75 + f] = srcp[i];
    }
    __syncthreads();
    if (t < nvalid) {
        float a0=0,a1=0,a2=0,a3=0,a4=0,a5=0,a6=0,a7=0,a8=0;
        const float* row = tile + t * 75;
        #pragma unroll 2
        for (int f = 0; f < N_FEATS; ++f) {
            float x = row[f];
            const float* wp = lw + f * 9;
            a0 += x * wp[0]; a1 += x * wp[1]; a2 += x * wp[2];
            a3 += x * wp[3]; a4 += x * wp[4]; a5 += x * wp[5];
            a6 += x * wp[6]; a7 += x * wp[7]; a8 += x * wp[8];
        }
        int i = base + t;
        sn4[i * 2]     = make_float4(a0, a1, a2, 0.f);  // el
        sn4[i * 2 + 1] = make_float4(a6, a7, a8, 0.f);  // hv
        er4[i]         = make_float4(a3, a4, a5, 0.f);
        nd4[i * 2]     = make_float4(0.f, 0.f, 0.f, 0.f);
        nd4[i * 2 + 1] = make_float4(0.f, 0.f, 0.f, 0.f);
    }
}

// ---- K4: edge pass, 2 edges/thread, packed atomics:
//      nd[d] = {num0,num1,num2,den0,den1,den2,_,_} ----
__global__ void kEdge(const int* __restrict__ src, const int* __restrict__ dst,
                      const float4* __restrict__ sn4, const float4* __restrict__ er4,
                      float* __restrict__ nd) {
    int e0 = (blockIdx.x * blockDim.x + threadIdx.x) * 2;
    if (e0 >= N_EDGES) return;
    int s0 = src[e0], d0 = dst[e0];
    int s1 = src[e0 + 1], d1 = dst[e0 + 1];
    // issue all gathers before any use (MLP x6)
    float4 L0 = sn4[s0 * 2];
    float4 V0 = sn4[s0 * 2 + 1];
    float4 R0 = er4[d0];
    float4 L1 = sn4[s1 * 2];
    float4 V1 = sn4[s1 * 2 + 1];
    float4 R1 = er4[d1];

    float x00 = expf(lrelu02(L0.x + R0.x));
    float x01 = expf(lrelu02(L0.y + R0.y));
    float x02 = expf(lrelu02(L0.z + R0.z));
    float* p0 = nd + (size_t)d0 * 8;
    pk_add(p0 + 0, x00 * V0.x, x01 * V0.y);
    pk_add(p0 + 2, x02 * V0.z, x00);
    pk_add(p0 + 4, x01, x02);

    float x10 = expf(lrelu02(L1.x + R1.x));
    float x11 = expf(lrelu02(L1.y + R1.y));
    float x12 = expf(lrelu02(L1.z + R1.z));
    float* p1 = nd + (size_t)d1 * 8;
    pk_add(p1 + 0, x10 * V1.x, x11 * V1.y);
    pk_add(p1 + 2, x12 * V1.z, x10);
    pk_add(p1 + 4, x11, x12);
}

// ---- K5: one wave per graph: y[g] = mean_i(sum_h num/den) + bgv + c0 ----
__global__ void kPoolFinal(const float4* __restrict__ nd4,
                           const float* __restrict__ bgv, const float* __restrict__ c0,
                           float* __restrict__ y) {
    int g = blockIdx.x * 4 + (threadIdx.x >> 6);
    int lane = threadIdx.x & 63;
    if (g >= N_GRAPHS) return;
    float c = 0.f;
    if (lane < 50) {
        int i = g * 50 + lane;
        float4 a = nd4[i * 2];      // num0,num1,num2,den0
        float4 b = nd4[i * 2 + 1];  // den1,den2,_,_
        if (a.w > 0.f) c = a.x / a.w + a.y / b.x + a.z / b.y;
    }
    c = waveReduceSum(c);
    if (!lane) y[g] = c * (1.f / 50.f) + bgv[0] + c0[0];
}

extern "C" void kernel_launch(void* const* d_in, const int* in_sizes, int n_in,
                              void* d_out, int out_size, void* d_ws, size_t ws_size,
                              hipStream_t stream) {
    const float* feats = (const float*)d_in[0];
    const float* W     = (const float*)d_in[1];
    const float* al    = (const float*)d_in[2];
    const float* ar    = (const float*)d_in[3];
    const float* bias  = (const float*)d_in[4];
    const float* W1    = (const float*)d_in[5];
    const float* b1    = (const float*)d_in[6];
    const float* W2    = (const float*)d_in[7];
    const float* b2    = (const float*)d_in[8];
    const int*   src   = (const int*)d_in[9];
    const int*   dst   = (const int*)d_in[10];

    float* ws  = (float*)d_ws;
    float* v   = ws;                      // 3072
    float* wl9 = ws + 3072;               // 672
    float* c0  = ws + 3744;               // 1
    float* bgv = ws + 3745;               // 1
    float* sn  = ws + 4096;               // N*8 (16B-aligned)
    float* er  = sn + N_NODES * 8;        // N*4
    float* nd  = er + N_NODES * 4;        // N*8
    float* y   = (float*)d_out;

    hipLaunchKernelGGL(kV, dim3((HD + 1 + N_FEATS * 3 + 3) / 4), dim3(256), 0, stream,
                       W1, W2, b1, b2, W, al, ar, v, c0, wl9);
    hipLaunchKernelGGL(kProj, dim3((N_FEATS * 3 + 1 + 3) / 4), dim3(256), 0, stream,
                       W, v, bias, wl9, bgv);
    hipLaunchKernelGGL(kNode, dim3((N_NODES + 255) / 256), dim3(256), 0, stream,
                       feats, wl9, (float4*)sn, (float4*)er, (float4*)nd);
    hipLaunchKernelGGL(kEdge, dim3((N_EDGES / 2 + 255) / 256), dim3(256), 0, stream,
                       src, dst, (const float4*)sn, (const float4*)er, nd);
    hipLaunchKernelGGL(kPoolFinal, dim3((N_GRAPHS + 3) / 4), dim3(256), 0, stream,
                       (const float4*)nd, bgv, c0, y);
}

// Round 7
// 82.223 us; speedup vs baseline: 1.1396x; 1.1396x over previous
//
#include <hip/hip_runtime.h>

#define N_NODES 40000
#define N_EDGES 160000
#define N_FEATS 74
#define DD 1024
#define HD 3072
#define N_GRAPHS 800

// binned-reduction geometry
#define NC 16            // edge chunks
#define NR 16            // dst ranges
#define RNG 2500         // dsts per range  (RNG*NR == N_NODES)
#define ECH 10000        // edges per chunk (ECH*NC == N_EDGES)

__device__ __forceinline__ float waveReduceSum(float v) {
    #pragma unroll
    for (int off = 32; off > 0; off >>= 1)
        v += __shfl_down(v, off, 64);
    return v;
}
__device__ __forceinline__ float lrelu02(float x) { return x > 0.f ? x : 0.2f * x; }

// ---- K1: v = W1@W2 (3072), c0 = b1.W2+b2, wl9 L/R columns (don't need v) ----
__global__ void kV(const float* __restrict__ W1, const float* __restrict__ W2,
                   const float* __restrict__ b1, const float* __restrict__ b2,
                   const float* __restrict__ W, const float* __restrict__ al,
                   const float* __restrict__ ar,
                   float* __restrict__ v, float* __restrict__ c0,
                   float* __restrict__ wl9) {
    int w = blockIdx.x * 4 + (threadIdx.x >> 6);
    int lane = threadIdx.x & 63;
    if (w < HD) {
        const float* row = W1 + (size_t)w * DD;
        float acc = 0.f;
        for (int t = lane; t < DD; t += 64) acc += row[t] * W2[t];
        acc = waveReduceSum(acc);
        if (!lane) v[w] = acc;
    } else if (w == HD) {
        float acc = 0.f;
        for (int t = lane; t < DD; t += 64) acc += b1[t] * W2[t];
        acc = waveReduceSum(acc);
        if (!lane) *c0 = acc + b2[0];
    } else if (w < HD + 1 + N_FEATS * 3) {
        int w2 = w - HD - 1;
        int f = w2 / 3, h = w2 - f * 3;
        const float* rw = W + (size_t)f * HD + h * DD;
        const float* pl = al + h * DD;
        const float* pr = ar + h * DD;
        float aL = 0.f, aR = 0.f;
        for (int t = lane; t < DD; t += 64) {
            float x = rw[t];
            aL += x * pl[t]; aR += x * pr[t];
        }
        aL = waveReduceSum(aL); aR = waveReduceSum(aR);
        if (!lane) { wl9[f * 9 + h] = aL; wl9[f * 9 + 3 + h] = aR; }
    }
}

// ---- K2: wl9 V column = W_col . v ; bgv = bias_gat . v (need v) ----
__global__ void kProj(const float* __restrict__ W, const float* __restrict__ v,
                      const float* __restrict__ bias,
                      float* __restrict__ wl9, float* __restrict__ bgv) {
    int w = blockIdx.x * 4 + (threadIdx.x >> 6);
    int lane = threadIdx.x & 63;
    if (w < N_FEATS * 3) {
        int f = w / 3, h = w - f * 3;
        const float* rw = W + (size_t)f * HD + h * DD;
        const float* pv = v + h * DD;
        float aV = 0.f;
        for (int t = lane; t < DD; t += 64) aV += rw[t] * pv[t];
        aV = waveReduceSum(aV);
        if (!lane) wl9[f * 9 + 6 + h] = aV;
    } else if (w == N_FEATS * 3) {
        float acc = 0.f;
        for (int t = lane; t < HD; t += 64) acc += bias[t] * v[t];
        acc = waveReduceSum(acc);
        if (!lane) *bgv = acc;
    }
}

// ---- K3: node projections; sn = [el|hv] packed 32B; er separate; zero nd ----
__global__ __launch_bounds__(256) void kNode(const float* __restrict__ feats,
                      const float* __restrict__ wl9,
                      float4* __restrict__ sn4,   // [N][2]: {el0..2,_},{hv0..2,_}
                      float4* __restrict__ er4,   // [N]
                      float4* __restrict__ nd4) { // [N][2] zeroed (for fallback path)
    __shared__ float tile[256 * 75];
    __shared__ float lw[N_FEATS * 9];
    int t = threadIdx.x;
    int base = blockIdx.x * 256;
    int nvalid = min(256, N_NODES - base);
    for (int i = t; i < N_FEATS * 9; i += 256) lw[i] = wl9[i];
    int total = nvalid * N_FEATS;
    const float* srcp = feats + (size_t)base * N_FEATS;
    for (int i = t; i < total; i += 256) {
        int node = i / N_FEATS;
        int f = i - node * N_FEATS;
        tile[node * 75 + f] = srcp[i];
    }
    __syncthreads();
    if (t < nvalid) {
        float a0=0,a1=0,a2=0,a3=0,a4=0,a5=0,a6=0,a7=0,a8=0;
        const float* row = tile + t * 75;
        #pragma unroll 2
        for (int f = 0; f < N_FEATS; ++f) {
            float x = row[f];
            const float* wp = lw + f * 9;
            a0 += x * wp[0]; a1 += x * wp[1]; a2 += x * wp[2];
            a3 += x * wp[3]; a4 += x * wp[4]; a5 += x * wp[5];
            a6 += x * wp[6]; a7 += x * wp[7]; a8 += x * wp[8];
        }
        int i = base + t;
        sn4[i * 2]     = make_float4(a0, a1, a2, 0.f);  // el
        sn4[i * 2 + 1] = make_float4(a6, a7, a8, 0.f);  // hv
        er4[i]         = make_float4(a3, a4, a5, 0.f);
        nd4[i * 2]     = make_float4(0.f, 0.f, 0.f, 0.f);
        nd4[i * 2 + 1] = make_float4(0.f, 0.f, 0.f, 0.f);
    }
}

// ---- K4a: binned scan — WG (chunk c, range r): LDS-accumulate, plain-store flush ----
__global__ __launch_bounds__(256) void kScan(const int* __restrict__ src,
                      const int* __restrict__ dst,
                      const float4* __restrict__ sn4, const float4* __restrict__ er4,
                      float* __restrict__ partial) {
    __shared__ float acc[RNG * 8];   // 80 KB
    int c = blockIdx.x >> 4;         // / NR
    int r = blockIdx.x & (NR - 1);   // % NR
    float4* acc4 = (float4*)acc;
    for (int i = threadIdx.x; i < RNG * 2; i += 256)
        acc4[i] = make_float4(0.f, 0.f, 0.f, 0.f);
    __syncthreads();
    const int rbase = r * RNG;
    const int ebase = c * ECH;
    for (int i = threadIdx.x; i < ECH; i += 256) {
        int e = ebase + i;
        int d = dst[e];
        unsigned rr = (unsigned)(d - rbase);
        if (rr < RNG) {
            int s = src[e];
            float4 L = sn4[s * 2];
            float4 V = sn4[s * 2 + 1];
            float4 R = er4[d];
            float e0 = expf(lrelu02(L.x + R.x));
            float e1 = expf(lrelu02(L.y + R.y));
            float e2 = expf(lrelu02(L.z + R.z));
            float* p = acc + rr * 8;
            atomicAdd(p + 0, e0 * V.x);   // num0
            atomicAdd(p + 1, e1 * V.y);   // num1
            atomicAdd(p + 2, e2 * V.z);   // num2
            atomicAdd(p + 3, e0);         // den0
            atomicAdd(p + 4, e1);         // den1
            atomicAdd(p + 5, e2);         // den2
        }
    }
    __syncthreads();
    float4* out4 = (float4*)(partial + (size_t)c * (N_NODES * 8) + (size_t)rbase * 8);
    for (int i = threadIdx.x; i < RNG * 2; i += 256)
        out4[i] = acc4[i];
}

// ---- K4b: nd = sum over chunks of partial copies ----
__global__ void kReduce(const float4* __restrict__ partial, float4* __restrict__ nd4) {
    int i = blockIdx.x * 256 + threadIdx.x;
    if (i >= N_NODES * 2) return;
    float4 s = make_float4(0.f, 0.f, 0.f, 0.f);
    #pragma unroll
    for (int c = 0; c < NC; ++c) {
        float4 p = partial[(size_t)c * (N_NODES * 2) + i];
        s.x += p.x; s.y += p.y; s.z += p.z; s.w += p.w;
    }
    nd4[i] = s;
}

// ---- K4-fallback: atomic edge pass (proven R4 path) ----
__global__ void kEdge(const int* __restrict__ src, const int* __restrict__ dst,
                      const float4* __restrict__ sn4, const float4* __restrict__ er4,
                      float* __restrict__ nd) {
    int e = blockIdx.x * blockDim.x + threadIdx.x;
    if (e >= N_EDGES) return;
    int s = src[e], d = dst[e];
    float4 L = sn4[s * 2];
    float4 V = sn4[s * 2 + 1];
    float4 R = er4[d];
    float e0 = expf(lrelu02(L.x + R.x));
    float e1 = expf(lrelu02(L.y + R.y));
    float e2 = expf(lrelu02(L.z + R.z));
    float* p = nd + (size_t)d * 8;
    atomicAdd(p + 0, e0 * V.x);
    atomicAdd(p + 1, e1 * V.y);
    atomicAdd(p + 2, e2 * V.z);
    atomicAdd(p + 3, e0);
    atomicAdd(p + 4, e1);
    atomicAdd(p + 5, e2);
}

// ---- K5: one wave per graph: y[g] = mean_i(sum_h num/den) + bgv + c0 ----
__global__ void kPoolFinal(const float4* __restrict__ nd4,
                           const float* __restrict__ bgv, const float* __restrict__ c0,
                           float* __restrict__ y) {
    int g = blockIdx.x * 4 + (threadIdx.x >> 6);
    int lane = threadIdx.x & 63;
    if (g >= N_GRAPHS) return;
    float c = 0.f;
    if (lane < 50) {
        int i = g * 50 + lane;
        float4 a = nd4[i * 2];      // num0,num1,num2,den0
        float4 b = nd4[i * 2 + 1];  // den1,den2,_,_
        if (a.w > 0.f) c = a.x / a.w + a.y / b.x + a.z / b.y;
    }
    c = waveReduceSum(c);
    if (!lane) y[g] = c * (1.f / 50.f) + bgv[0] + c0[0];
}

extern "C" void kernel_launch(void* const* d_in, const int* in_sizes, int n_in,
                              void* d_out, int out_size, void* d_ws, size_t ws_size,
                              hipStream_t stream) {
    const float* feats = (const float*)d_in[0];
    const float* W     = (const float*)d_in[1];
    const float* al    = (const float*)d_in[2];
    const float* ar    = (const float*)d_in[3];
    const float* bias  = (const float*)d_in[4];
    const float* W1    = (const float*)d_in[5];
    const float* b1    = (const float*)d_in[6];
    const float* W2    = (const float*)d_in[7];
    const float* b2    = (const float*)d_in[8];
    const int*   src   = (const int*)d_in[9];
    const int*   dst   = (const int*)d_in[10];

    float* ws  = (float*)d_ws;
    float* v   = ws;                      // 3072
    float* wl9 = ws + 3072;               // 672
    float* c0  = ws + 3744;               // 1
    float* bgv = ws + 3745;               // 1
    float* sn  = ws + 4096;               // N*8 (16B-aligned)
    float* er  = sn + N_NODES * 8;        // N*4
    float* nd  = er + N_NODES * 4;        // N*8
    float* par = nd + N_NODES * 8;        // NC*N*8 (binned path only)
    float* y   = (float*)d_out;

    const size_t need_floats = 4096 + (size_t)N_NODES * (8 + 4 + 8) + (size_t)NC * N_NODES * 8;

    hipLaunchKernelGGL(kV, dim3((HD + 1 + N_FEATS * 3 + 3) / 4), dim3(256), 0, stream,
                       W1, W2, b1, b2, W, al, ar, v, c0, wl9);
    hipLaunchKernelGGL(kProj, dim3((N_FEATS * 3 + 1 + 3) / 4), dim3(256), 0, stream,
                       W, v, bias, wl9, bgv);
    hipLaunchKernelGGL(kNode, dim3((N_NODES + 255) / 256), dim3(256), 0, stream,
                       feats, wl9, (float4*)sn, (float4*)er, (float4*)nd);
    if (ws_size >= need_floats * sizeof(float)) {
        hipLaunchKernelGGL(kScan, dim3(NC * NR), dim3(256), 0, stream,
                           src, dst, (const float4*)sn, (const float4*)er, par);
        hipLaunchKernelGGL(kReduce, dim3((N_NODES * 2 + 255) / 256), dim3(256), 0, stream,
                           (const float4*)par, (float4*)nd);
    } else {
        hipLaunchKernelGGL(kEdge, dim3((N_EDGES + 255) / 256), dim3(256), 0, stream,
                           src, dst, (const float4*)sn, (const float4*)er, nd);
    }
    hipLaunchKernelGGL(kPoolFinal, dim3((N_GRAPHS + 3) / 4), dim3(256), 0, stream,
                       (const float4*)nd, bgv, c0, y);
}

// Round 8
// 76.963 us; speedup vs baseline: 1.2175x; 1.0684x over previous
//
#include <hip/hip_runtime.h>

#define N_NODES 40000
#define N_EDGES 160000
#define N_FEATS 74
#define DD 1024
#define HD 3072
#define N_GRAPHS 800

// binned-reduction geometry
#define NC 16            // edge chunks
#define NR 64            // dst ranges
#define RNG 625          // dsts per range  (RNG*NR == N_NODES)
#define ECH 10000        // edges per chunk (ECH*NC == N_EDGES)

__device__ __forceinline__ float waveReduceSum(float v) {
    #pragma unroll
    for (int off = 32; off > 0; off >>= 1)
        v += __shfl_down(v, off, 64);
    return v;
}
__device__ __forceinline__ float lrelu02(float x) { return x > 0.f ? x : 0.2f * x; }

// ---- K1: v = W1@W2 (3072), c0 = b1.W2+b2, wl9 L/R columns (don't need v) ----
__global__ void kV(const float* __restrict__ W1, const float* __restrict__ W2,
                   const float* __restrict__ b1, const float* __restrict__ b2,
                   const float* __restrict__ W, const float* __restrict__ al,
                   const float* __restrict__ ar,
                   float* __restrict__ v, float* __restrict__ c0,
                   float* __restrict__ wl9) {
    int w = blockIdx.x * 4 + (threadIdx.x >> 6);
    int lane = threadIdx.x & 63;
    if (w < HD) {
        const float* row = W1 + (size_t)w * DD;
        float acc = 0.f;
        for (int t = lane; t < DD; t += 64) acc += row[t] * W2[t];
        acc = waveReduceSum(acc);
        if (!lane) v[w] = acc;
    } else if (w == HD) {
        float acc = 0.f;
        for (int t = lane; t < DD; t += 64) acc += b1[t] * W2[t];
        acc = waveReduceSum(acc);
        if (!lane) *c0 = acc + b2[0];
    } else if (w < HD + 1 + N_FEATS * 3) {
        int w2 = w - HD - 1;
        int f = w2 / 3, h = w2 - f * 3;
        const float* rw = W + (size_t)f * HD + h * DD;
        const float* pl = al + h * DD;
        const float* pr = ar + h * DD;
        float aL = 0.f, aR = 0.f;
        for (int t = lane; t < DD; t += 64) {
            float x = rw[t];
            aL += x * pl[t]; aR += x * pr[t];
        }
        aL = waveReduceSum(aL); aR = waveReduceSum(aR);
        if (!lane) { wl9[f * 9 + h] = aL; wl9[f * 9 + 3 + h] = aR; }
    }
}

// ---- K2: wl9 V column = W_col . v ; bgv = bias_gat . v (need v) ----
__global__ void kProj(const float* __restrict__ W, const float* __restrict__ v,
                      const float* __restrict__ bias,
                      float* __restrict__ wl9, float* __restrict__ bgv) {
    int w = blockIdx.x * 4 + (threadIdx.x >> 6);
    int lane = threadIdx.x & 63;
    if (w < N_FEATS * 3) {
        int f = w / 3, h = w - f * 3;
        const float* rw = W + (size_t)f * HD + h * DD;
        const float* pv = v + h * DD;
        float aV = 0.f;
        for (int t = lane; t < DD; t += 64) aV += rw[t] * pv[t];
        aV = waveReduceSum(aV);
        if (!lane) wl9[f * 9 + 6 + h] = aV;
    } else if (w == N_FEATS * 3) {
        float acc = 0.f;
        for (int t = lane; t < HD; t += 64) acc += bias[t] * v[t];
        acc = waveReduceSum(acc);
        if (!lane) *bgv = acc;
    }
}

// ---- K3: node projections; sn = [el|hv] packed 32B; er separate; zero nd ----
__global__ __launch_bounds__(256) void kNode(const float* __restrict__ feats,
                      const float* __restrict__ wl9,
                      float4* __restrict__ sn4,   // [N][2]: {el0..2,_},{hv0..2,_}
                      float4* __restrict__ er4,   // [N]
                      float* __restrict__ nd) {   // [N][6] zeroed (for fallback path)
    __shared__ float tile[256 * 75];
    __shared__ float lw[N_FEATS * 9];
    int t = threadIdx.x;
    int base = blockIdx.x * 256;
    int nvalid = min(256, N_NODES - base);
    for (int i = t; i < N_FEATS * 9; i += 256) lw[i] = wl9[i];
    int total = nvalid * N_FEATS;
    const float* srcp = feats + (size_t)base * N_FEATS;
    for (int i = t; i < total; i += 256) {
        int node = i / N_FEATS;
        int f = i - node * N_FEATS;
        tile[node * 75 + f] = srcp[i];
    }
    __syncthreads();
    if (t < nvalid) {
        float a0=0,a1=0,a2=0,a3=0,a4=0,a5=0,a6=0,a7=0,a8=0;
        const float* row = tile + t * 75;
        #pragma unroll 2
        for (int f = 0; f < N_FEATS; ++f) {
            float x = row[f];
            const float* wp = lw + f * 9;
            a0 += x * wp[0]; a1 += x * wp[1]; a2 += x * wp[2];
            a3 += x * wp[3]; a4 += x * wp[4]; a5 += x * wp[5];
            a6 += x * wp[6]; a7 += x * wp[7]; a8 += x * wp[8];
        }
        int i = base + t;
        sn4[i * 2]     = make_float4(a0, a1, a2, 0.f);  // el
        sn4[i * 2 + 1] = make_float4(a6, a7, a8, 0.f);  // hv
        er4[i]         = make_float4(a3, a4, a5, 0.f);
        float2* ndz = (float2*)(nd + (size_t)i * 6);
        ndz[0] = make_float2(0.f, 0.f);
        ndz[1] = make_float2(0.f, 0.f);
        ndz[2] = make_float2(0.f, 0.f);
    }
}

// ---- K4a: binned scan — WG (chunk c, range r): LDS-accumulate, plain-store flush ----
// acc layout per node in range: {n0,n1,n2,d0,d1,d2}, stride 6
__global__ __launch_bounds__(256) void kScan(const int* __restrict__ src,
                      const int* __restrict__ dst,
                      const float4* __restrict__ sn4, const float4* __restrict__ er4,
                      float* __restrict__ partial) {
    __shared__ float acc[RNG * 6];   // 15 KB -> 4+ WGs/CU resident
    int c = blockIdx.x >> 6;         // / NR
    int r = blockIdx.x & (NR - 1);   // % NR
    float2* acc2 = (float2*)acc;
    for (int i = threadIdx.x; i < RNG * 3; i += 256)
        acc2[i] = make_float2(0.f, 0.f);
    __syncthreads();
    const int rbase = r * RNG;
    const int ebase = c * ECH;
    for (int i = threadIdx.x; i < ECH; i += 256) {
        int e = ebase + i;
        int d = dst[e];
        unsigned rr = (unsigned)(d - rbase);
        if (rr < RNG) {
            int s = src[e];
            float4 L = sn4[s * 2];
            float4 V = sn4[s * 2 + 1];
            float4 R = er4[d];
            float e0 = expf(lrelu02(L.x + R.x));
            float e1 = expf(lrelu02(L.y + R.y));
            float e2 = expf(lrelu02(L.z + R.z));
            float* p = acc + rr * 6;
            atomicAdd(p + 0, e0 * V.x);   // num0
            atomicAdd(p + 1, e1 * V.y);   // num1
            atomicAdd(p + 2, e2 * V.z);   // num2
            atomicAdd(p + 3, e0);         // den0
            atomicAdd(p + 4, e1);         // den1
            atomicAdd(p + 5, e2);         // den2
        }
    }
    __syncthreads();
    float2* out2 = (float2*)(partial + (size_t)c * (N_NODES * 6) + (size_t)rbase * 6);
    for (int i = threadIdx.x; i < RNG * 3; i += 256)
        out2[i] = acc2[i];
}

// ---- K4b: nd = sum over chunk copies (float4-wise over the flat [N*6] array) ----
__global__ void kReduce(const float4* __restrict__ partial, float4* __restrict__ nd4) {
    int i = blockIdx.x * 256 + threadIdx.x;
    if (i >= N_NODES * 6 / 4) return;
    float4 s = make_float4(0.f, 0.f, 0.f, 0.f);
    #pragma unroll
    for (int c = 0; c < NC; ++c) {
        float4 p = partial[(size_t)c * (N_NODES * 6 / 4) + i];
        s.x += p.x; s.y += p.y; s.z += p.z; s.w += p.w;
    }
    nd4[i] = s;
}

// ---- K4-fallback: atomic edge pass (proven R4 path), 6-stride ----
__global__ void kEdge(const int* __restrict__ src, const int* __restrict__ dst,
                      const float4* __restrict__ sn4, const float4* __restrict__ er4,
                      float* __restrict__ nd) {
    int e = blockIdx.x * blockDim.x + threadIdx.x;
    if (e >= N_EDGES) return;
    int s = src[e], d = dst[e];
    float4 L = sn4[s * 2];
    float4 V = sn4[s * 2 + 1];
    float4 R = er4[d];
    float e0 = expf(lrelu02(L.x + R.x));
    float e1 = expf(lrelu02(L.y + R.y));
    float e2 = expf(lrelu02(L.z + R.z));
    float* p = nd + (size_t)d * 6;
    atomicAdd(p + 0, e0 * V.x);
    atomicAdd(p + 1, e1 * V.y);
    atomicAdd(p + 2, e2 * V.z);
    atomicAdd(p + 3, e0);
    atomicAdd(p + 4, e1);
    atomicAdd(p + 5, e2);
}

// ---- K5: one wave per graph: y[g] = mean_i(sum_h num/den) + bgv + c0 ----
__global__ void kPoolFinal(const float* __restrict__ nd,
                           const float* __restrict__ bgv, const float* __restrict__ c0,
                           float* __restrict__ y) {
    int g = blockIdx.x * 4 + (threadIdx.x >> 6);
    int lane = threadIdx.x & 63;
    if (g >= N_GRAPHS) return;
    float c = 0.f;
    if (lane < 50) {
        const float* p = nd + (size_t)(g * 50 + lane) * 6;
        float2 a = *(const float2*)(p + 0);   // n0,n1
        float2 b = *(const float2*)(p + 2);   // n2,d0
        float2 dd = *(const float2*)(p + 4);  // d1,d2
        if (b.y > 0.f) c = a.x / b.y + a.y / dd.x + b.x / dd.y;
    }
    c = waveReduceSum(c);
    if (!lane) y[g] = c * (1.f / 50.f) + bgv[0] + c0[0];
}

extern "C" void kernel_launch(void* const* d_in, const int* in_sizes, int n_in,
                              void* d_out, int out_size, void* d_ws, size_t ws_size,
                              hipStream_t stream) {
    const float* feats = (const float*)d_in[0];
    const float* W     = (const float*)d_in[1];
    const float* al    = (const float*)d_in[2];
    const float* ar    = (const float*)d_in[3];
    const float* bias  = (const float*)d_in[4];
    const float* W1    = (const float*)d_in[5];
    const float* b1    = (const float*)d_in[6];
    const float* W2    = (const float*)d_in[7];
    const float* b2    = (const float*)d_in[8];
    const int*   src   = (const int*)d_in[9];
    const int*   dst   = (const int*)d_in[10];

    float* ws  = (float*)d_ws;
    float* v   = ws;                      // 3072
    float* wl9 = ws + 3072;               // 672
    float* c0  = ws + 3744;               // 1
    float* bgv = ws + 3745;               // 1
    float* sn  = ws + 4096;               // N*8 (16B-aligned)
    float* er  = sn + N_NODES * 8;        // N*4
    float* nd  = er + N_NODES * 4;        // N*6
    float* par = nd + N_NODES * 6;        // NC*N*6 (binned path only; 16B-aligned: N*18 even)
    float* y   = (float*)d_out;

    const size_t need_floats = 4096 + (size_t)N_NODES * (8 + 4 + 6) + (size_t)NC * N_NODES * 6;

    hipLaunchKernelGGL(kV, dim3((HD + 1 + N_FEATS * 3 + 3) / 4), dim3(256), 0, stream,
                       W1, W2, b1, b2, W, al, ar, v, c0, wl9);
    hipLaunchKernelGGL(kProj, dim3((N_FEATS * 3 + 1 + 3) / 4), dim3(256), 0, stream,
                       W, v, bias, wl9, bgv);
    hipLaunchKernelGGL(kNode, dim3((N_NODES + 255) / 256), dim3(256), 0, stream,
                       feats, wl9, (float4*)sn, (float4*)er, nd);
    if (ws_size >= need_floats * sizeof(float)) {
        hipLaunchKernelGGL(kScan, dim3(NC * NR), dim3(256), 0, stream,
                           src, dst, (const float4*)sn, (const float4*)er, par);
        hipLaunchKernelGGL(kReduce, dim3((N_NODES * 6 / 4 + 255) / 256), dim3(256), 0, stream,
                           (const float4*)par, (float4*)nd);
    } else {
        hipLaunchKernelGGL(kEdge, dim3((N_EDGES + 255) / 256), dim3(256), 0, stream,
                           src, dst, (const float4*)sn, (const float4*)er, nd);
    }
    hipLaunchKernelGGL(kPoolFinal, dim3((N_GRAPHS + 3) / 4), dim3(256), 0, stream,
                       nd, bgv, c0, y);
}